// Round 2
// baseline (721.787 us; speedup 1.0000x reference)
//
#include <hip/hip_runtime.h>

// LocallyConnected3DFlipout:
//   out[b,p,f] = sum_k patch[b,p,k]*loc[p,k,f]
//              + sign_out[b,p,f]*sum_k (x*sign_in)patch[b,p,k]*(softplus(rho)*eps)[p,k,f]
//              + bias[f]
// patch k = c*27 + (kd*9+kh*3+kw)  (channel slowest, spatial row-major fastest).
//
// R2 design: lanes are p-fastest (16 consecutive p per 16-lane cluster ->
// 256 B contiguous global runs for x/sign_in/sign_out/out). Each thread
// handles 2 batches (b, b+16) for 2x load MLP and half the LDS reads per
// FLOP. Weights staged in LDS as bf16, mean+noise packed in one uint4 per
// (p, k): one ds_read_b128 -> all 8 weights a tap-channel needs.

constexpr int Bn   = 32;
constexpr int Dn   = 30;
constexpr int Cn   = 4;
constexpr int ODn  = 28;
constexpr int Pn   = ODn * ODn * ODn;   // 21952
constexpr int Tt   = 27;
constexpr int Kn   = Tt * Cn;           // 108
constexpr int PPB  = 16;                // positions per block
constexpr int THREADS = 256;            // 16 p x 16 b-pairs
constexpr int WSTRIDE = Kn + 1;         // 109 uint4 per p: pad -> p-stride 436 dwords
                                        // (436 mod 32 = 20 -> 2-way max, free)

__device__ __forceinline__ unsigned bf16rne(float f) {
    unsigned u = __float_as_uint(f);
    return (u + 0x7fffu + ((u >> 16) & 1u)) >> 16;
}
__device__ __forceinline__ float bflo(unsigned u) { return __uint_as_float(u << 16); }
__device__ __forceinline__ float bfhi(unsigned u) { return __uint_as_float(u & 0xffff0000u); }

__global__ __launch_bounds__(THREADS, 5) void lc3d_flipout_kernel(
    const float* __restrict__ x,        // [B,30,30,30,4]
    const float* __restrict__ loc,      // [P,108,4]
    const float* __restrict__ rho,      // [P,108,4]
    const float* __restrict__ bias,     // [4]
    const float* __restrict__ eps,      // [P,108,4]
    const float* __restrict__ sgn_in,   // [B,30,30,30,4]
    const float* __restrict__ sgn_out,  // [B,P,4]
    float* __restrict__ out)            // [B,P,4]
{
    // LDS: [p_loc][k] -> uint4 { packed bf16 mean f0..f3 (.x,.y),
    //                            packed bf16 noise f0..f3 (.z,.w) }
    __shared__ uint4 w[PPB * WSTRIDE];   // 27904 B -> 5 blocks/CU

    const int tid    = threadIdx.x;
    const int p_base = blockIdx.x * PPB;

    // ---- Stage weights: PPB*Kn = 1728 uint4; global reads coalesced over g,
    //      LDS writes sequential b128 (k fastest) -> conflict-free. ----
    const float4* loc4 = (const float4*)loc + (size_t)p_base * Kn;
    const float4* rho4 = (const float4*)rho + (size_t)p_base * Kn;
    const float4* eps4 = (const float4*)eps + (size_t)p_base * Kn;

    for (int g = tid; g < PPB * Kn; g += THREADS) {
        const int pl = g / Kn;
        const int k  = g - pl * Kn;
        const float4 L = loc4[g];
        const float4 R = rho4[g];
        const float4 E = eps4[g];
        float nx = (R.x > 15.f ? R.x : __logf(1.f + __expf(R.x))) * E.x;
        float ny = (R.y > 15.f ? R.y : __logf(1.f + __expf(R.y))) * E.y;
        float nz = (R.z > 15.f ? R.z : __logf(1.f + __expf(R.z))) * E.z;
        float nw = (R.w > 15.f ? R.w : __logf(1.f + __expf(R.w))) * E.w;
        uint4 pk;
        pk.x = bf16rne(L.x) | (bf16rne(L.y) << 16);
        pk.y = bf16rne(L.z) | (bf16rne(L.w) << 16);
        pk.z = bf16rne(nx)  | (bf16rne(ny) << 16);
        pk.w = bf16rne(nz)  | (bf16rne(nw) << 16);
        w[pl * WSTRIDE + k] = pk;
    }
    __syncthreads();

    // ---- Compute: lane = (bh, pl), thread does batches bh and bh+16 ----
    const int pl = tid & 15;
    const int bh = tid >> 4;            // 0..15
    const int b0 = bh, b1 = bh + 16;
    const int p  = p_base + pl;
    const int od   = p / (ODn * ODn);
    const int prem = p - od * (ODn * ODn);
    const int oh   = prem / ODn;
    const int ow   = prem - oh * ODn;

    const float4* x4 = (const float4*)x;
    const float4* s4 = (const float4*)sgn_in;
    const size_t v0 = (((size_t)b0 * Dn + od) * Dn + oh) * Dn + ow;
    const size_t v1 = (((size_t)b1 * Dn + od) * Dn + oh) * Dn + ow;
    const uint4* wp = w + pl * WSTRIDE;

    float a00=0.f,a01=0.f,a02=0.f,a03=0.f;   // mean acc, batch b0
    float a10=0.f,a11=0.f,a12=0.f,a13=0.f;   // mean acc, batch b1
    float n00=0.f,n01=0.f,n02=0.f,n03=0.f;   // noise acc, batch b0
    float n10=0.f,n11=0.f,n12=0.f,n13=0.f;   // noise acc, batch b1

#define CHAN(c, xa_c, sa_c, xb_c, sb_c)                                      \
    {                                                                        \
        const uint4 wv = wp[(c) * Tt + t];                                   \
        const float m0 = bflo(wv.x), m1 = bfhi(wv.x);                        \
        const float m2 = bflo(wv.y), m3 = bfhi(wv.y);                        \
        const float q0 = bflo(wv.z), q1 = bfhi(wv.z);                        \
        const float q2 = bflo(wv.w), q3 = bfhi(wv.w);                        \
        a00 = fmaf(xa_c, m0, a00); a01 = fmaf(xa_c, m1, a01);                \
        a02 = fmaf(xa_c, m2, a02); a03 = fmaf(xa_c, m3, a03);                \
        a10 = fmaf(xb_c, m0, a10); a11 = fmaf(xb_c, m1, a11);                \
        a12 = fmaf(xb_c, m2, a12); a13 = fmaf(xb_c, m3, a13);                \
        const float ya = (xa_c) * (sa_c);                                    \
        const float yb = (xb_c) * (sb_c);                                    \
        n00 = fmaf(ya, q0, n00); n01 = fmaf(ya, q1, n01);                    \
        n02 = fmaf(ya, q2, n02); n03 = fmaf(ya, q3, n03);                    \
        n10 = fmaf(yb, q0, n10); n11 = fmaf(yb, q1, n11);                    \
        n12 = fmaf(yb, q2, n12); n13 = fmaf(yb, q3, n13);                    \
    }

    #pragma unroll
    for (int kd = 0; kd < 3; ++kd) {
        #pragma unroll
        for (int kh = 0; kh < 3; ++kh) {
            const int roff = (kd * Dn + kh) * Dn;
            const float4* xr0 = x4 + v0 + roff;
            const float4* sr0 = s4 + v0 + roff;
            const float4* xr1 = x4 + v1 + roff;
            const float4* sr1 = s4 + v1 + roff;
            #pragma unroll
            for (int kw = 0; kw < 3; ++kw) {
                const int t = (kd * 3 + kh) * 3 + kw;
                const float4 xa = xr0[kw];
                const float4 sa = sr0[kw];
                const float4 xb = xr1[kw];
                const float4 sb = sr1[kw];
                CHAN(0, xa.x, sa.x, xb.x, sb.x);
                CHAN(1, xa.y, sa.y, xb.y, sb.y);
                CHAN(2, xa.z, sa.z, xb.z, sb.z);
                CHAN(3, xa.w, sa.w, xb.w, sb.w);
            }
        }
    }
#undef CHAN

    // ---- Epilogue: coalesced (16 consecutive p per cluster) ----
    const float4 bi = *(const float4*)bias;
    const size_t ob0 = (size_t)b0 * Pn + p;
    const size_t ob1 = (size_t)b1 * Pn + p;
    const float4 so0 = ((const float4*)sgn_out)[ob0];
    const float4 so1 = ((const float4*)sgn_out)[ob1];
    float4 o0, o1;
    o0.x = fmaf(so0.x, n00, a00) + bi.x;
    o0.y = fmaf(so0.y, n01, a01) + bi.y;
    o0.z = fmaf(so0.z, n02, a02) + bi.z;
    o0.w = fmaf(so0.w, n03, a03) + bi.w;
    o1.x = fmaf(so1.x, n10, a10) + bi.x;
    o1.y = fmaf(so1.y, n11, a11) + bi.y;
    o1.z = fmaf(so1.z, n12, a12) + bi.z;
    o1.w = fmaf(so1.w, n13, a13) + bi.w;
    ((float4*)out)[ob0] = o0;
    ((float4*)out)[ob1] = o1;
}

extern "C" void kernel_launch(void* const* d_in, const int* in_sizes, int n_in,
                              void* d_out, int out_size, void* d_ws, size_t ws_size,
                              hipStream_t stream) {
    const float* x    = (const float*)d_in[0];
    const float* loc  = (const float*)d_in[1];
    const float* rho  = (const float*)d_in[2];
    const float* bias = (const float*)d_in[3];
    const float* eps  = (const float*)d_in[4];
    const float* si   = (const float*)d_in[5];
    const float* so   = (const float*)d_in[6];
    float* out = (float*)d_out;

    lc3d_flipout_kernel<<<dim3(Pn / PPB), dim3(THREADS), 0, stream>>>(
        x, loc, rho, bias, eps, si, so, out);
}

// Round 3
// 217.504 us; speedup vs baseline: 3.3185x; 3.3185x over previous
//
#include <hip/hip_runtime.h>

// LocallyConnected3DFlipout:
//   out[b,p,f] = sum_k patch[b,p,k]*loc[p,k,f]
//              + sign_out[b,p,f]*sum_k (x*sign_in)patch[b,p,k]*(softplus(rho)*eps)[p,k,f]
//              + bias[f]
// patch k = c*27 + (kd*9+kh*3+kw)  (channel slowest, spatial row-major fastest).
//
// R3: R2 structure with the register clamp removed. R2's __launch_bounds__(256,5)
// capped VGPRs (~reported 48) and spilled the 16 inner-loop accumulators to
// scratch: WRITE_SIZE 11 MB -> 1.44 GB, 613 us. Plain __launch_bounds__(256)
// (R1 allocated 52 spill-free) lets the allocator hold the accumulators;
// LDS (27.9 KB -> 5 blocks/CU) is the intended occupancy limiter.
//
// Structure: lanes p-fastest (16 consecutive p per 16-lane cluster ->
// 256 B contiguous global runs for x/sign_in/sign_out/out). Each thread
// handles 2 batches (b, b+16). Weights staged in LDS as bf16, mean+noise
// packed in one uint4 per (p,k): one ds_read_b128 -> all 8 weights of a
// (tap,channel). bf16 weights verified: absmax 0.0156 vs 0.0578 threshold.

constexpr int Bn   = 32;
constexpr int Dn   = 30;
constexpr int Cn   = 4;
constexpr int ODn  = 28;
constexpr int Pn   = ODn * ODn * ODn;   // 21952
constexpr int Tt   = 27;
constexpr int Kn   = Tt * Cn;           // 108
constexpr int PPB  = 16;                // positions per block
constexpr int THREADS = 256;            // 16 p x 16 b-pairs
constexpr int WSTRIDE = Kn + 1;         // 109 uint4 per p -> p-stride 436 dwords
                                        // (436 mod 32 = 20 -> worst 2-way, free)

__device__ __forceinline__ unsigned bf16rne(float f) {
    unsigned u = __float_as_uint(f);
    return (u + 0x7fffu + ((u >> 16) & 1u)) >> 16;
}
__device__ __forceinline__ float bflo(unsigned u) { return __uint_as_float(u << 16); }
__device__ __forceinline__ float bfhi(unsigned u) { return __uint_as_float(u & 0xffff0000u); }

__global__ __launch_bounds__(THREADS) void lc3d_flipout_kernel(
    const float* __restrict__ x,        // [B,30,30,30,4]
    const float* __restrict__ loc,      // [P,108,4]
    const float* __restrict__ rho,      // [P,108,4]
    const float* __restrict__ bias,     // [4]
    const float* __restrict__ eps,      // [P,108,4]
    const float* __restrict__ sgn_in,   // [B,30,30,30,4]
    const float* __restrict__ sgn_out,  // [B,P,4]
    float* __restrict__ out)            // [B,P,4]
{
    // LDS: [p_loc][k] -> uint4 { packed bf16 mean f0..f3 (.x,.y),
    //                            packed bf16 noise f0..f3 (.z,.w) }
    __shared__ uint4 w[PPB * WSTRIDE];

    const int tid    = threadIdx.x;
    const int p_base = blockIdx.x * PPB;

    // ---- Stage weights: PPB*Kn = 1728 uint4; global reads coalesced over g,
    //      LDS writes sequential b128 (k fastest) -> conflict-free. ----
    const float4* loc4 = (const float4*)loc + (size_t)p_base * Kn;
    const float4* rho4 = (const float4*)rho + (size_t)p_base * Kn;
    const float4* eps4 = (const float4*)eps + (size_t)p_base * Kn;

    for (int g = tid; g < PPB * Kn; g += THREADS) {
        const int pl = g / Kn;
        const int k  = g - pl * Kn;
        const float4 L = loc4[g];
        const float4 R = rho4[g];
        const float4 E = eps4[g];
        float nx = (R.x > 15.f ? R.x : __logf(1.f + __expf(R.x))) * E.x;
        float ny = (R.y > 15.f ? R.y : __logf(1.f + __expf(R.y))) * E.y;
        float nz = (R.z > 15.f ? R.z : __logf(1.f + __expf(R.z))) * E.z;
        float nw = (R.w > 15.f ? R.w : __logf(1.f + __expf(R.w))) * E.w;
        uint4 pk;
        pk.x = bf16rne(L.x) | (bf16rne(L.y) << 16);
        pk.y = bf16rne(L.z) | (bf16rne(L.w) << 16);
        pk.z = bf16rne(nx)  | (bf16rne(ny) << 16);
        pk.w = bf16rne(nz)  | (bf16rne(nw) << 16);
        w[pl * WSTRIDE + k] = pk;
    }
    __syncthreads();

    // ---- Compute: lane = (bh, pl), thread does batches bh and bh+16 ----
    const int pl = tid & 15;
    const int bh = tid >> 4;            // 0..15
    const int b0 = bh, b1 = bh + 16;
    const int p  = p_base + pl;
    const int od   = p / (ODn * ODn);
    const int prem = p - od * (ODn * ODn);
    const int oh   = prem / ODn;
    const int ow   = prem - oh * ODn;

    const float4* x4 = (const float4*)x;
    const float4* s4 = (const float4*)sgn_in;
    const size_t v0 = (((size_t)b0 * Dn + od) * Dn + oh) * Dn + ow;
    const size_t v1 = (((size_t)b1 * Dn + od) * Dn + oh) * Dn + ow;
    const uint4* wp = w + pl * WSTRIDE;

    float a00=0.f,a01=0.f,a02=0.f,a03=0.f;   // mean acc, batch b0
    float a10=0.f,a11=0.f,a12=0.f,a13=0.f;   // mean acc, batch b1
    float n00=0.f,n01=0.f,n02=0.f,n03=0.f;   // noise acc, batch b0
    float n10=0.f,n11=0.f,n12=0.f,n13=0.f;   // noise acc, batch b1

#define CHAN(c, xa_c, sa_c, xb_c, sb_c)                                      \
    {                                                                        \
        const uint4 wv = wp[(c) * Tt + t];                                   \
        const float m0 = bflo(wv.x), m1 = bfhi(wv.x);                        \
        const float m2 = bflo(wv.y), m3 = bfhi(wv.y);                        \
        const float q0 = bflo(wv.z), q1 = bfhi(wv.z);                        \
        const float q2 = bflo(wv.w), q3 = bfhi(wv.w);                        \
        a00 = fmaf(xa_c, m0, a00); a01 = fmaf(xa_c, m1, a01);                \
        a02 = fmaf(xa_c, m2, a02); a03 = fmaf(xa_c, m3, a03);                \
        a10 = fmaf(xb_c, m0, a10); a11 = fmaf(xb_c, m1, a11);                \
        a12 = fmaf(xb_c, m2, a12); a13 = fmaf(xb_c, m3, a13);                \
        const float ya = (xa_c) * (sa_c);                                    \
        const float yb = (xb_c) * (sb_c);                                    \
        n00 = fmaf(ya, q0, n00); n01 = fmaf(ya, q1, n01);                    \
        n02 = fmaf(ya, q2, n02); n03 = fmaf(ya, q3, n03);                    \
        n10 = fmaf(yb, q0, n10); n11 = fmaf(yb, q1, n11);                    \
        n12 = fmaf(yb, q2, n12); n13 = fmaf(yb, q3, n13);                    \
    }

    #pragma unroll
    for (int kd = 0; kd < 3; ++kd) {
        #pragma unroll
        for (int kh = 0; kh < 3; ++kh) {
            const int roff = (kd * Dn + kh) * Dn;
            const float4* xr0 = x4 + v0 + roff;
            const float4* sr0 = s4 + v0 + roff;
            const float4* xr1 = x4 + v1 + roff;
            const float4* sr1 = s4 + v1 + roff;
            #pragma unroll
            for (int kw = 0; kw < 3; ++kw) {
                const int t = (kd * 3 + kh) * 3 + kw;
                const float4 xa = xr0[kw];
                const float4 sa = sr0[kw];
                const float4 xb = xr1[kw];
                const float4 sb = sr1[kw];
                CHAN(0, xa.x, sa.x, xb.x, sb.x);
                CHAN(1, xa.y, sa.y, xb.y, sb.y);
                CHAN(2, xa.z, sa.z, xb.z, sb.z);
                CHAN(3, xa.w, sa.w, xb.w, sb.w);
            }
        }
    }
#undef CHAN

    // ---- Epilogue: coalesced (16 consecutive p per cluster) ----
    const float4 bi = *(const float4*)bias;
    const size_t ob0 = (size_t)b0 * Pn + p;
    const size_t ob1 = (size_t)b1 * Pn + p;
    const float4 so0 = ((const float4*)sgn_out)[ob0];
    const float4 so1 = ((const float4*)sgn_out)[ob1];
    float4 o0, o1;
    o0.x = fmaf(so0.x, n00, a00) + bi.x;
    o0.y = fmaf(so0.y, n01, a01) + bi.y;
    o0.z = fmaf(so0.z, n02, a02) + bi.z;
    o0.w = fmaf(so0.w, n03, a03) + bi.w;
    o1.x = fmaf(so1.x, n10, a10) + bi.x;
    o1.y = fmaf(so1.y, n11, a11) + bi.y;
    o1.z = fmaf(so1.z, n12, a12) + bi.z;
    o1.w = fmaf(so1.w, n13, a13) + bi.w;
    ((float4*)out)[ob0] = o0;
    ((float4*)out)[ob1] = o1;
}

extern "C" void kernel_launch(void* const* d_in, const int* in_sizes, int n_in,
                              void* d_out, int out_size, void* d_ws, size_t ws_size,
                              hipStream_t stream) {
    const float* x    = (const float*)d_in[0];
    const float* loc  = (const float*)d_in[1];
    const float* rho  = (const float*)d_in[2];
    const float* bias = (const float*)d_in[3];
    const float* eps  = (const float*)d_in[4];
    const float* si   = (const float*)d_in[5];
    const float* so   = (const float*)d_in[6];
    float* out = (float*)d_out;

    lc3d_flipout_kernel<<<dim3(Pn / PPB), dim3(THREADS), 0, stream>>>(
        x, loc, rho, bias, eps, si, so, out);
}